// Round 10
// baseline (54.143 us; speedup 1.0000x reference)
//
#include <hip/hip_runtime.h>
#include <hip/hip_bf16.h>
#include <math.h>

// TokenCompressor: B=8, N=16384, C=128, BLOCK=32, STRIDE=16 -> nb=1023
// Decomposition: chunks c of 16 tokens; A = x.view(8192, 2048) (contiguous!)
//   P[m, 0:256]  = chunk[m] @ W1[0:2048]
//   P[m, 256:512]= chunk[m] @ W1[2048:4096]
//   h[j] = gelu(P[j,0:256] + P[j+1,256:512] + b1 + posflat@W1)
//   out[j] = h[j] @ W2 + b2
// R10: restore cross-block overlap (R9 post-mortem: 1 block/CU -> every
// barrier stalls the whole CU; m97's 874 TF explicitly rides on ~3
// blocks/CU implicit overlap). m97-shaped iteration: 128x128 tile, BK=32,
// 4 waves, per-wave 64x64 acc[4][4] (12 ds_read : 16 MFMA), split-K=2 ->
// grid 512 = 2 blocks/CU (LDS 48KB). A stays f32 in LDS (cvt_pk at frag
// read); both operands via gload_lds w/ pre-swizzled source; counted
// vmcnt(6); 2 partials summed in k_comb.

typedef __attribute__((ext_vector_type(8))) short short8;
typedef __attribute__((ext_vector_type(4))) float f4;

#define OFF_BT   0u                          // 512x2048 bf16 = 2 MB
#define OFF_W2T  (2u << 20)                  // 128x256 bf16 = 64 KB
#define OFF_PART ((2u << 20) + (64u << 10))  // 64x256 f32 = 64 KB
#define OFF_BIAS ((2u << 20) + (128u << 10)) // 256 f32
#define OFF_P    (4u << 20)                  // 2 x (8192x512) bf16 = 16 MB

static __device__ __forceinline__ unsigned short f2bf(float f) {
  union { float f; unsigned u; } v; v.f = f;
  return (unsigned short)((v.u + 0x7FFFu + ((v.u >> 16) & 1u)) >> 16);
}
static __device__ __forceinline__ float bf2f(unsigned short h) {
  union { unsigned u; float f; } v; v.u = ((unsigned)h) << 16;
  return v.f;
}
static __device__ __forceinline__ void gload_lds16(const void* g, void* l) {
  __builtin_amdgcn_global_load_lds(
      (const __attribute__((address_space(1))) void*)g,
      (__attribute__((address_space(3))) void*)l, 16, 0, 0);
}

// ---- k_prep: blocks 0..255: W1 -> Bt (512x2048 bf16, n-major) + bias parts
//              blocks 256..383: W2 (256x128 f32) -> W2t (128x256 bf16, T)
__global__ __launch_bounds__(256) void k_prep(const float* __restrict__ W1,
                                              const float* __restrict__ pos,
                                              const float* __restrict__ W2,
                                              unsigned short* __restrict__ Bt,
                                              unsigned short* __restrict__ W2t,
                                              float* __restrict__ part) {
  __shared__ float T[64][65];
  const int w = blockIdx.x;
  const int t = threadIdx.x;
  if (w >= 256) {
    const int n = w - 256;
    W2t[n * 256 + t] = f2bf(W2[t * 128 + n]);
    return;
  }
  const int h = w >> 7, rem = w & 127, kt = rem >> 2, nt = rem & 3;
  const int krow0 = h * 2048 + kt * 64, col0 = nt * 64;
  const int lr = t >> 2, lc = (t & 3) * 16;
  const float* src = W1 + (size_t)(krow0 + lr) * 256 + col0 + lc;
#pragma unroll
  for (int i = 0; i < 4; ++i) {
    f4 v = *(const f4*)(src + i * 4);
#pragma unroll
    for (int q = 0; q < 4; ++q) T[lr][lc + i * 4 + q] = v[q];
  }
  __syncthreads();
  if (t < 64) {
    float s = 0.f;
#pragma unroll 8
    for (int k = 0; k < 64; ++k) s += T[k][t] * pos[krow0 + k];
    part[(h * 32 + kt) * 256 + col0 + t] = s;
  }
  const int nl = t >> 2, kc = (t & 3) * 16;
  short8 o0, o1;
#pragma unroll
  for (int i = 0; i < 8; ++i) o0[i] = (short)f2bf(T[kc + i][nl]);
#pragma unroll
  for (int i = 0; i < 8; ++i) o1[i] = (short)f2bf(T[kc + 8 + i][nl]);
  unsigned short* dst = Bt + (size_t)(256 * h + col0 + nl) * 2048 + kt * 64 + kc;
  *(short8*)dst = o0;
  *(short8*)(dst + 8) = o1;
}

// ---- k_bias ------------------------------------------------------------
__global__ __launch_bounds__(256) void k_bias(const float* __restrict__ b1,
                                              const float* __restrict__ part,
                                              float* __restrict__ bias) {
  int n = threadIdx.x;
  float s = b1[n];
#pragma unroll 8
  for (int g = 0; g < 64; ++g) s += part[g * 256 + n];
  bias[n] = s;
}

// ---- k_gemm: Ppart[ksp] (8192x512 bf16) = X(f32)[:,ksp*1024:+1024]@Bt^T --
// 128x128 tile, BK=32, 32 steps. 256 thr = 4 waves (2x2), per-wave 64x64
// acc[4][4]. Grid 512 = 2 blocks/CU. LDS/buf: A 128x32 f32 (16KB,
// 8 chunks/row, ch^=(row&7)) + B 128x32 bf16 (8KB, 4 chunks/row,
// ch^=(row&3)) = 24KB; 2 bufs = 48KB. Counted vmcnt(6).
__global__ __launch_bounds__(256, 2) void k_gemm(const float* __restrict__ X,
                                                 const unsigned short* __restrict__ Bt,
                                                 unsigned short* __restrict__ P) {
  __shared__ __align__(16) char lds[2][24576];  // A f32 16KB | B bf16 8KB
  const int orig = blockIdx.x;
  const int wg = (orig & 7) * 64 + (orig >> 3);  // bijective (512%8==0)
  const int mt = wg >> 3;          // 0..63  (XCD keeps an 8-mt band)
  const int nt = (wg >> 1) & 3;    // 0..3
  const int ksp = wg & 1;          // 0..1
  const int m0 = mt * 128, n0 = nt * 128, k0 = ksp * 1024;
  const int t = threadIdx.x;
  const int wid = t >> 6, lane = t & 63;
  const int wm = (wid >> 1) * 64, wn = (wid & 1) * 64;

  f4 acc[4][4];
#pragma unroll
  for (int i = 0; i < 4; ++i)
#pragma unroll
    for (int j = 0; j < 4; ++j) acc[i][j] = f4{0.f, 0.f, 0.f, 0.f};

  // 6 gload_lds per thread per tile: 4 A (f32) + 2 B (bf16).
  // A slot s=ii*256+t: row=s>>3, c8=s&7, src chunk = c8 ^ (row&7).
  // B slot s=ii*256+t: row=s>>2, c4=s&3, src chunk = c4 ^ (row&3).
#define ISSUE(BUF, KT)                                                     \
  do {                                                                     \
    const int kf = k0 + (KT) * 32;                                         \
    _Pragma("unroll") for (int ii = 0; ii < 4; ++ii) {                     \
      const int s = ii * 256 + t;                                          \
      const int row = s >> 3, c8 = s & 7;                                  \
      gload_lds16(X + (size_t)(m0 + row) * 2048 + kf +                     \
                      ((c8 ^ (row & 7)) << 2),                             \
                  &lds[BUF][ii * 4096 + wid * 1024]);                      \
    }                                                                      \
    _Pragma("unroll") for (int ii = 0; ii < 2; ++ii) {                     \
      const int s = ii * 256 + t;                                          \
      const int row = s >> 2, c4 = s & 3;                                  \
      gload_lds16(Bt + (size_t)(n0 + row) * 2048 + kf +                    \
                      ((c4 ^ (row & 3)) << 3),                             \
                  &lds[BUF][16384 + ii * 4096 + wid * 1024]);              \
    }                                                                      \
  } while (0)

  // per wave: 8 A-b128 (f32 lo/hi) + 16 cvt_pk + 4 B-b128 + 16 MFMA.
#define COMPUTE(BUF)                                                       \
  do {                                                                     \
    const float* Ab = (const float*)&lds[BUF][0];                          \
    const unsigned short* Bb = (const unsigned short*)&lds[BUF][16384];    \
    short8 af[4], bfv[4];                                                  \
    const int jk = lane >> 4;                                              \
    _Pragma("unroll") for (int m = 0; m < 4; ++m) {                        \
      const int row = wm + m * 16 + (lane & 15);                           \
      const int e = row & 7;                                               \
      f4 lo = *(const f4*)(Ab + row * 32 + (((2 * jk) ^ e) << 2));         \
      f4 hi = *(const f4*)(Ab + row * 32 + (((2 * jk + 1) ^ e) << 2));     \
      union { short8 s8; unsigned u[4]; } pk;                              \
      asm("v_cvt_pk_bf16_f32 %0, %1, %2" : "=v"(pk.u[0])                   \
          : "v"(lo[0]), "v"(lo[1]));                                       \
      asm("v_cvt_pk_bf16_f32 %0, %1, %2" : "=v"(pk.u[1])                   \
          : "v"(lo[2]), "v"(lo[3]));                                       \
      asm("v_cvt_pk_bf16_f32 %0, %1, %2" : "=v"(pk.u[2])                   \
          : "v"(hi[0]), "v"(hi[1]));                                       \
      asm("v_cvt_pk_bf16_f32 %0, %1, %2" : "=v"(pk.u[3])                   \
          : "v"(hi[2]), "v"(hi[3]));                                       \
      af[m] = pk.s8;                                                       \
    }                                                                      \
    _Pragma("unroll") for (int n = 0; n < 4; ++n) {                        \
      const int row = wn + n * 16 + (lane & 15);                           \
      bfv[n] = *(const short8*)(Bb + row * 32 +                            \
                                ((jk ^ (row & 3)) << 3));                  \
    }                                                                      \
    __builtin_amdgcn_s_setprio(1);                                         \
    _Pragma("unroll") for (int m = 0; m < 4; ++m)                          \
      _Pragma("unroll") for (int n = 0; n < 4; ++n)                        \
        acc[m][n] = __builtin_amdgcn_mfma_f32_16x16x32_bf16(               \
            af[m], bfv[n], acc[m][n], 0, 0, 0);                            \
    __builtin_amdgcn_s_setprio(0);                                         \
  } while (0)

  // prologue: tiles 0,1 in flight (12 DMAs); wait tile 0 (leave 6)
  ISSUE(0, 0);
  ISSUE(1, 1);
  __builtin_amdgcn_sched_barrier(0);
  asm volatile("s_waitcnt vmcnt(6)" ::: "memory");
  __builtin_amdgcn_s_barrier();
  __builtin_amdgcn_sched_barrier(0);

#pragma unroll 2
  for (int kt = 0; kt < 32; ++kt) {
    COMPUTE(kt & 1);
    __builtin_amdgcn_sched_barrier(0);
    __builtin_amdgcn_s_barrier();  // all waves done reading buf kt&1
    __builtin_amdgcn_sched_barrier(0);
    if (kt < 30) {
      ISSUE(kt & 1, kt + 2);       // 6 new; <=12 in flight
      __builtin_amdgcn_sched_barrier(0);
      asm volatile("s_waitcnt vmcnt(6)" ::: "memory");  // tile kt+1 landed
      __builtin_amdgcn_s_barrier();
      __builtin_amdgcn_sched_barrier(0);
    } else if (kt == 30) {
      asm volatile("s_waitcnt vmcnt(0)" ::: "memory");  // tile 31 landed
      __builtin_amdgcn_s_barrier();
      __builtin_amdgcn_sched_barrier(0);
    }
  }
#undef ISSUE
#undef COMPUTE

  // epilogue: partial write. C/D layout: col=lane&15, row=(lane>>4)*4+reg
  unsigned short* Pp = P + (size_t)ksp * (8192 * 512);
  const int mb = m0 + wm, nb = n0 + wn;
#pragma unroll
  for (int m = 0; m < 4; ++m)
#pragma unroll
    for (int n = 0; n < 4; ++n) {
      const int row0 = mb + m * 16 + ((lane >> 4) << 2);
      const int col = nb + n * 16 + (lane & 15);
#pragma unroll
      for (int r = 0; r < 4; ++r)
        Pp[(size_t)(row0 + r) * 512 + col] = f2bf(acc[m][n][r]);
    }
}

// ---- k_comb: h=gelu(Pa0+Pb0+Pa1+Pb1+bias); out = h@W2 + b2 -------------
__global__ __launch_bounds__(256) void k_comb(const unsigned short* __restrict__ P,
                                              const unsigned short* __restrict__ W2t,
                                              const float* __restrict__ bias,
                                              const float* __restrict__ b2,
                                              float* __restrict__ out) {
  __shared__ unsigned short W2s[128 * 256];
  __shared__ unsigned short Hs[32 * 256];
  const unsigned short* Pa = P;
  const unsigned short* Pb = P + (size_t)8192 * 512;
  const int wg = blockIdx.x;
  const int b = wg >> 5, jt = wg & 31;
  const int j0 = jt * 32;
  const int t = threadIdx.x;

  {  // stage W2t
    const int row = t >> 1, halfc = (t & 1) * 128;
    const unsigned short* src = W2t + row * 256 + halfc;
    const int cbw = halfc >> 3;
#pragma unroll
    for (int i = 0; i < 16; ++i) {
      short8 v = *(const short8*)(src + i * 8);
      const int c = (cbw + i) ^ (row & 7);
      *(short8*)&W2s[row * 256 + c * 8] = v;
    }
  }
  {  // h rows
    const int r = t >> 3, seg = t & 7;
    const int j = j0 + r;
    const size_t m = (size_t)b * 1024 + j;
    const size_t mp1 = (j < 1023) ? m + 1 : m;
    const unsigned short* p0a = Pa + m * 512 + seg * 32;
    const unsigned short* p0b = Pb + m * 512 + seg * 32;
    const unsigned short* p1a = Pa + mp1 * 512 + 256 + seg * 32;
    const unsigned short* p1b = Pb + mp1 * 512 + 256 + seg * 32;
    const float* bs = bias + seg * 32;
    const int cbh = seg * 4;
#pragma unroll
    for (int i = 0; i < 4; ++i) {
      short8 v0a = *(const short8*)(p0a + i * 8);
      short8 v0b = *(const short8*)(p0b + i * 8);
      short8 v1a = *(const short8*)(p1a + i * 8);
      short8 v1b = *(const short8*)(p1b + i * 8);
      short8 pk;
#pragma unroll
      for (int q = 0; q < 8; ++q) {
        float f = bf2f((unsigned short)v0a[q]) + bf2f((unsigned short)v0b[q]) +
                  bf2f((unsigned short)v1a[q]) + bf2f((unsigned short)v1b[q]) +
                  bs[i * 8 + q];
        float g = 0.5f * f * (1.f + erff(f * 0.70710678118f));
        pk[q] = (short)f2bf(g);
      }
      const int c = (cbh + i) ^ (r & 7);
      *(short8*)&Hs[r * 256 + c * 8] = pk;
    }
  }
  __syncthreads();

  const int wid = t >> 6, lane = t & 63;
  f4 acc[2][2];
#pragma unroll
  for (int i = 0; i < 2; ++i)
#pragma unroll
    for (int j = 0; j < 2; ++j) acc[i][j] = f4{0.f, 0.f, 0.f, 0.f};

#pragma unroll
  for (int ks = 0; ks < 8; ++ks) {
    short8 af[2], bfr[2];
    const int cc = ks * 4 + (lane >> 4);
#pragma unroll
    for (int f = 0; f < 2; ++f) {
      const int ra = f * 16 + (lane & 15);
      af[f] = *(const short8*)&Hs[ra * 256 + ((cc ^ (ra & 7)) << 3)];
      const int rb = wid * 32 + f * 16 + (lane & 15);
      bfr[f] = *(const short8*)&W2s[rb * 256 + ((cc ^ (rb & 7)) << 3)];
    }
#pragma unroll
    for (int i = 0; i < 2; ++i)
#pragma unroll
      for (int j = 0; j < 2; ++j)
        acc[i][j] = __builtin_amdgcn_mfma_f32_16x16x32_bf16(af[i], bfr[j],
                                                            acc[i][j], 0, 0, 0);
  }
#pragma unroll
  for (int i = 0; i < 2; ++i)
#pragma unroll
    for (int j = 0; j < 2; ++j) {
      const int row0 = i * 16 + ((lane >> 4) << 2);
      const int col = wid * 32 + j * 16 + (lane & 15);
      const float bb = b2[col];
#pragma unroll
      for (int r = 0; r < 4; ++r) {
        const int jj = j0 + row0 + r;
        if (jj < 1023)
          out[((size_t)b * 1023 + jj) * 128 + col] = acc[i][j][r] + bb;
      }
    }
}

extern "C" void kernel_launch(void* const* d_in, const int* in_sizes, int n_in,
                              void* d_out, int out_size, void* d_ws, size_t ws_size,
                              hipStream_t stream) {
  const float* x   = (const float*)d_in[0];
  const float* pos = (const float*)d_in[1];
  const float* W1  = (const float*)d_in[2];
  const float* b1  = (const float*)d_in[3];
  const float* W2  = (const float*)d_in[4];
  const float* b2  = (const float*)d_in[5];
  float* out = (float*)d_out;
  char* ws = (char*)d_ws;
  unsigned short* Bt  = (unsigned short*)(ws + OFF_BT);
  unsigned short* W2t = (unsigned short*)(ws + OFF_W2T);
  float* part         = (float*)(ws + OFF_PART);
  float* bias         = (float*)(ws + OFF_BIAS);
  unsigned short* P   = (unsigned short*)(ws + OFF_P);

  k_prep<<<384, 256, 0, stream>>>(W1, pos, W2, Bt, W2t, part);
  k_bias<<<1, 256, 0, stream>>>(b1, part, bias);
  k_gemm<<<512, 256, 0, stream>>>(x, Bt, P);
  k_comb<<<256, 256, 0, stream>>>(P, W2t, bias, b2, out);
}